// Round 3
// baseline (189.962 us; speedup 1.0000x reference)
//
#include <hip/hip_runtime.h>
#include <math.h>

#define NN 3072
#define NH 8
#define FO 64
#define FCAT 512
#define MAXDEG 128
#define ALPHA 0.2f

typedef __attribute__((ext_vector_type(8))) short bf16x8;
typedef __attribute__((ext_vector_type(4))) float f32x4;

static __device__ __forceinline__ unsigned short f2bf(float v) {
    union { float f; unsigned u; } x; x.f = v;
    unsigned r = x.u + 0x7fffu + ((x.u >> 16) & 1u);
    return (unsigned short)(r >> 16);
}
static __device__ __forceinline__ float bf2f(unsigned short b) {
    union { unsigned u; float f; } x; x.u = ((unsigned)b) << 16;
    return x.f;
}

// ---------------- CSR build: one wave per row, ballot-ordered (deterministic) ----------------
__global__ __launch_bounds__(64) void build_csr_k(const float* __restrict__ adj,
                                                  int* __restrict__ deg,
                                                  int* __restrict__ nbr) {
    int row = blockIdx.x;
    int lane = threadIdx.x;
    const float* arow = adj + (size_t)row * NN;
    int count = 0;
    for (int base = 0; base < NN; base += 64) {
        float v = arow[base + lane];
        unsigned long long m = __ballot(v > 0.0f);
        if (v > 0.0f) {
            int pos = count + __popcll(m & ((1ull << lane) - 1ull));
            if (pos < MAXDEG) nbr[(size_t)row * MAXDEG + pos] = base + lane;
        }
        count += __popcll(m);
    }
    if (lane == 0) deg[row] = count < MAXDEG ? count : MAXDEG;
}

// ---------------- x -> bf16 hi/lo ----------------
__global__ __launch_bounds__(256) void conv_x_k(const float* __restrict__ x,
                                                unsigned short* __restrict__ xh,
                                                unsigned short* __restrict__ xl, int n) {
    int i = blockIdx.x * 256 + threadIdx.x;
    if (i < n) {
        float v = x[i];
        unsigned short hb = f2bf(v);
        xh[i] = hb;
        xl[i] = f2bf(v - bf2f(hb));
    }
}

// ---------------- W[h][k][o] -> Wt[h][o][k] split to bf16 hi/lo ----------------
__global__ __launch_bounds__(256) void conv_wt_k(const float* __restrict__ W1,
                                                 const float* __restrict__ W2,
                                                 const float* __restrict__ W3,
                                                 const float* __restrict__ W4,
                                                 unsigned short* __restrict__ Wth,
                                                 unsigned short* __restrict__ Wtl) {
    __shared__ float t[64][65];
    int b = blockIdx.x;
    const float* W; int K; int local; size_t obase;
    if (b < 16)       { W = W1; K = 128; local = b;       obase = 0; }
    else if (b < 80)  { W = W2; K = 512; local = b - 16;  obase = 65536; }
    else if (b < 144) { W = W3; K = 512; local = b - 80;  obase = 327680; }
    else              { W = W4; K = 512; local = b - 144; obase = 589824; }
    int nkt = K >> 6;
    int h = local / nkt, kt = local - h * nkt;
    int k0 = kt * 64;
    int tid = threadIdx.x;
    for (int idx = tid; idx < 4096; idx += 256) {
        int r = idx >> 6, c = idx & 63;
        t[r][c] = W[(size_t)h * K * FO + (size_t)(k0 + r) * FO + c];
    }
    __syncthreads();
    for (int idx = tid; idx < 4096; idx += 256) {
        int o = idx >> 6, kk = idx & 63;
        float v = t[kk][o];
        unsigned short hb = f2bf(v);
        size_t dst = obase + (size_t)(h * FO + o) * K + k0 + kk;
        Wth[dst] = hb;
        Wtl[dst] = f2bf(v - bf2f(hb));
    }
}

// ---------------- split-bf16 MFMA GEMM + fused e_src/e_dst epilogue ----------------
// grid (NH, NN/64); block 256 = 4 waves; C[n, h*64+o]; ee[n][0..7]=esrc, [8..15]=edst
__global__ __launch_bounds__(256) void gemm_ee_k(const unsigned short* __restrict__ Ah,
                                                 const unsigned short* __restrict__ Al,
                                                 const unsigned short* __restrict__ Bh,
                                                 const unsigned short* __restrict__ Bl,
                                                 const float* __restrict__ a,
                                                 float* __restrict__ C,
                                                 float* __restrict__ ee, int K) {
    __shared__ __align__(16) unsigned char smem[40960];
    typedef unsigned short AsT[64][80];
    typedef float CsT[68];
    AsT* As = reinterpret_cast<AsT*>(smem);            // As[2][64][80] hi/lo (20480 B)
    AsT* Bs = reinterpret_cast<AsT*>(smem + 20480);    // Bs[2][64][80]
    CsT* Cs = reinterpret_cast<CsT*>(smem);            // Cs[64][68] overlays As after final sync

    const int tid = threadIdx.x;
    const int h = blockIdx.x;
    const int r0 = blockIdx.y * 64;
    const int lane = tid & 63;
    const int wid = tid >> 6;
    const int wr = wid >> 1, wc = wid & 1;
    const int lr = lane & 15, lg = lane >> 4;

    const unsigned short* Bhh = Bh + (size_t)h * FO * K;
    const unsigned short* Bll = Bl + (size_t)h * FO * K;

    f32x4 acc[2][2];
    #pragma unroll
    for (int i = 0; i < 2; ++i)
        #pragma unroll
        for (int j = 0; j < 2; ++j) acc[i][j] = (f32x4){0.f, 0.f, 0.f, 0.f};

    for (int k0 = 0; k0 < K; k0 += 64) {
        #pragma unroll
        for (int half = 0; half < 2; ++half) {
            int q = tid + half * 256;
            int row = q >> 3, cq = q & 7;
            int sw = (cq ^ (row & 7)) * 8;
            size_t ga = (size_t)(r0 + row) * K + k0 + cq * 8;
            *(bf16x8*)&As[0][row][sw] = *(const bf16x8*)(Ah + ga);
            *(bf16x8*)&As[1][row][sw] = *(const bf16x8*)(Al + ga);
            size_t gb = (size_t)row * K + k0 + cq * 8;
            *(bf16x8*)&Bs[0][row][sw] = *(const bf16x8*)(Bhh + gb);
            *(bf16x8*)&Bs[1][row][sw] = *(const bf16x8*)(Bll + gb);
        }
        __syncthreads();
        #pragma unroll
        for (int ks = 0; ks < 2; ++ks) {
            bf16x8 ah[2], al[2], bh[2], bl[2];
            #pragma unroll
            for (int i = 0; i < 2; ++i) {
                int cq = ks * 4 + lg;
                int row = wr * 32 + i * 16 + lr;
                int offa = (cq ^ (row & 7)) * 8;
                ah[i] = *(const bf16x8*)&As[0][row][offa];
                al[i] = *(const bf16x8*)&As[1][row][offa];
                int col = wc * 32 + i * 16 + lr;
                int offb = (cq ^ (col & 7)) * 8;
                bh[i] = *(const bf16x8*)&Bs[0][col][offb];
                bl[i] = *(const bf16x8*)&Bs[1][col][offb];
            }
            #pragma unroll
            for (int i = 0; i < 2; ++i)
                #pragma unroll
                for (int j = 0; j < 2; ++j) {
                    acc[i][j] = __builtin_amdgcn_mfma_f32_16x16x32_bf16(ah[i], bh[j], acc[i][j], 0, 0, 0);
                    acc[i][j] = __builtin_amdgcn_mfma_f32_16x16x32_bf16(ah[i], bl[j], acc[i][j], 0, 0, 0);
                    acc[i][j] = __builtin_amdgcn_mfma_f32_16x16x32_bf16(al[i], bh[j], acc[i][j], 0, 0, 0);
                }
        }
        __syncthreads();
    }

    // stage C tile in LDS (fp32)
    #pragma unroll
    for (int i = 0; i < 2; ++i)
        #pragma unroll
        for (int j = 0; j < 2; ++j)
            #pragma unroll
            for (int r = 0; r < 4; ++r)
                Cs[wr * 32 + i * 16 + lg * 4 + r][wc * 32 + j * 16 + lr] = acc[i][j][r];
    __syncthreads();

    // coalesced float4 C stores
    #pragma unroll
    for (int it = 0; it < 4; ++it) {
        int idx = tid + it * 256;
        int r = idx >> 4, c4 = idx & 15;
        *(float4*)&C[(size_t)(r0 + r) * FCAT + h * FO + c4 * 4] = *(float4*)&Cs[r][c4 * 4];
    }

    // fused e_src/e_dst: wave w handles rows w*16..w*16+15
    float as_ = a[h * 2 * FO + lane];
    float ad_ = a[h * 2 * FO + FO + lane];
    #pragma unroll
    for (int i = 0; i < 16; ++i) {
        int r = wid * 16 + i;
        float v = Cs[r][lane];
        float s = v * as_;
        float dd = v * ad_;
        #pragma unroll
        for (int off = 32; off; off >>= 1) {
            s += __shfl_xor(s, off);
            dd += __shfl_xor(dd, off);
        }
        if (lane == 0) {
            ee[(size_t)(r0 + r) * 16 + h] = s;
            ee[(size_t)(r0 + r) * 16 + 8 + h] = dd;
        }
    }
}

// ---------------- attention + aggregation: one block per node, 8 waves = 8 heads ----------------
__global__ __launch_bounds__(512) void attn_agg2_k(const float* __restrict__ Wh,
                                                   const float* __restrict__ ee,
                                                   const int* __restrict__ deg,
                                                   const int* __restrict__ nbr,
                                                   float* __restrict__ outp,
                                                   unsigned short* __restrict__ oh,
                                                   unsigned short* __restrict__ ol,
                                                   int write_f32) {
    __shared__ int jb[MAXDEG];
    __shared__ float edl[MAXDEG][8];   // per-neighbor edst for all 8 heads
    __shared__ float pb[NH][MAXDEG];
    const int tid = threadIdx.x;
    const int h = tid >> 6;
    const int lane = tid & 63;
    const int n = blockIdx.x;
    const int d = deg[n];

    if (h == 0) {
        for (int t = lane; t < d; t += 64) {
            int j = nbr[(size_t)n * MAXDEG + t];
            jb[t] = j;
            float4 e0 = *(const float4*)&ee[(size_t)j * 16 + 8];
            float4 e1 = *(const float4*)&ee[(size_t)j * 16 + 12];
            *(float4*)&edl[t][0] = e0;
            *(float4*)&edl[t][4] = e1;
        }
    }
    __syncthreads();

    // per-head softmax (each wave independent after this point)
    float es = ee[(size_t)n * 16 + h];
    float lm = -3.0e38f;
    for (int t = lane; t < d; t += 64) {
        float e = es + edl[t][h];
        e = (e > 0.0f) ? e : ALPHA * e;
        pb[h][t] = e;
        lm = fmaxf(lm, e);
    }
    #pragma unroll
    for (int off = 32; off; off >>= 1) lm = fmaxf(lm, __shfl_xor(lm, off));
    float lsum = 0.0f;
    for (int t = lane; t < d; t += 64) {
        float pv = __expf(pb[h][t] - lm);
        pb[h][t] = pv;
        lsum += pv;
    }
    #pragma unroll
    for (int off = 32; off; off >>= 1) lsum += __shfl_xor(lsum, off);

    // aggregation: 4 lane-groups x 16 lanes; group g handles neighbors t = g, g+4, ...
    const int g = lane >> 4, l = lane & 15;
    float4 acc = {0.f, 0.f, 0.f, 0.f};
    for (int t = g; t < d; t += 4) {
        float pv = pb[h][t];
        const float4* row = (const float4*)(Wh + (size_t)jb[t] * FCAT + h * FO);
        float4 v = row[l];
        acc.x = fmaf(pv, v.x, acc.x);
        acc.y = fmaf(pv, v.y, acc.y);
        acc.z = fmaf(pv, v.z, acc.z);
        acc.w = fmaf(pv, v.w, acc.w);
    }
    #pragma unroll
    for (int off = 32; off >= 16; off >>= 1) {
        acc.x += __shfl_xor(acc.x, off);
        acc.y += __shfl_xor(acc.y, off);
        acc.z += __shfl_xor(acc.z, off);
        acc.w += __shfl_xor(acc.w, off);
    }
    float inv = 1.0f / lsum;
    acc.x *= inv; acc.y *= inv; acc.z *= inv; acc.w *= inv;
    acc.x = (acc.x > 0.0f) ? acc.x : (__expf(acc.x) - 1.0f);
    acc.y = (acc.y > 0.0f) ? acc.y : (__expf(acc.y) - 1.0f);
    acc.z = (acc.z > 0.0f) ? acc.z : (__expf(acc.z) - 1.0f);
    acc.w = (acc.w > 0.0f) ? acc.w : (__expf(acc.w) - 1.0f);

    if (g == 0) {
        size_t idx = (size_t)n * FCAT + h * FO + l * 4;
        if (write_f32) {
            *(float4*)&outp[idx] = acc;
        } else {
            unsigned short h0 = f2bf(acc.x), h1 = f2bf(acc.y), h2 = f2bf(acc.z), h3 = f2bf(acc.w);
            unsigned short l0 = f2bf(acc.x - bf2f(h0)), l1 = f2bf(acc.y - bf2f(h1));
            unsigned short l2 = f2bf(acc.z - bf2f(h2)), l3 = f2bf(acc.w - bf2f(h3));
            ushort4 hv = {h0, h1, h2, h3};
            ushort4 lv = {l0, l1, l2, l3};
            *(ushort4*)&oh[idx] = hv;
            *(ushort4*)&ol[idx] = lv;
        }
    }
}

extern "C" void kernel_launch(void* const* d_in, const int* in_sizes, int n_in,
                              void* d_out, int out_size, void* d_ws, size_t ws_size,
                              hipStream_t stream) {
    const float* x   = (const float*)d_in[0];
    const float* adj = (const float*)d_in[1];
    const float* ap[4] = {(const float*)d_in[3], (const float*)d_in[5],
                          (const float*)d_in[7], (const float*)d_in[9]};
    float* out = (float*)d_out;

    char* p = (char*)d_ws;
    int* deg = (int*)p;              p += (size_t)NN * sizeof(int);
    int* nbr = (int*)p;              p += (size_t)NN * MAXDEG * sizeof(int);
    unsigned short* Ah = (unsigned short*)p; p += (size_t)NN * FCAT * 2;
    unsigned short* Al = (unsigned short*)p; p += (size_t)NN * FCAT * 2;
    float* WhF = (float*)p;          p += (size_t)NN * FCAT * sizeof(float);
    unsigned short* Wth = (unsigned short*)p; p += (size_t)851968 * 2;
    unsigned short* Wtl = (unsigned short*)p; p += (size_t)851968 * 2;
    float* ee = (float*)p;           p += (size_t)NN * 16 * sizeof(float);

    build_csr_k<<<NN, 64, 0, stream>>>(adj, deg, nbr);
    conv_x_k<<<(NN * 128 + 255) / 256, 256, 0, stream>>>(x, Ah, Al, NN * 128);
    conv_wt_k<<<208, 256, 0, stream>>>((const float*)d_in[2], (const float*)d_in[4],
                                       (const float*)d_in[6], (const float*)d_in[8],
                                       Wth, Wtl);

    const size_t woff[4] = {0, 65536, 327680, 589824};
    int K = 128;
    for (int L = 0; L < 4; ++L) {
        dim3 g(NH, NN / 64);
        gemm_ee_k<<<g, 256, 0, stream>>>(Ah, Al, Wth + woff[L], Wtl + woff[L],
                                         ap[L], WhF, ee, K);
        attn_agg2_k<<<NN, 512, 0, stream>>>(WhF, ee, deg, nbr,
                                            out, Ah, Al, L == 3 ? 1 : 0);
        K = FCAT;
    }
}

// Round 4
// 184.677 us; speedup vs baseline: 1.0286x; 1.0286x over previous
//
#include <hip/hip_runtime.h>
#include <math.h>

#define NN 3072
#define NH 8
#define FO 64
#define FCAT 512
#define MAXDEG 128
#define ALPHA 0.2f

typedef __attribute__((ext_vector_type(8))) short bf16x8;
typedef __attribute__((ext_vector_type(4))) float f32x4;

static __device__ __forceinline__ unsigned short f2bf(float v) {
    union { float f; unsigned u; } x; x.f = v;
    unsigned r = x.u + 0x7fffu + ((x.u >> 16) & 1u);
    return (unsigned short)(r >> 16);
}
static __device__ __forceinline__ float bf2f(unsigned short b) {
    union { unsigned u; float f; } x; x.u = ((unsigned)b) << 16;
    return x.f;
}

// ---------------- CSR build: one wave per row, ballot-ordered (deterministic) ----------------
__global__ __launch_bounds__(64) void build_csr_k(const float* __restrict__ adj,
                                                  int* __restrict__ deg,
                                                  int* __restrict__ nbr) {
    int row = blockIdx.x;
    int lane = threadIdx.x;
    const float* arow = adj + (size_t)row * NN;
    int count = 0;
    for (int base = 0; base < NN; base += 64) {
        float v = arow[base + lane];
        unsigned long long m = __ballot(v > 0.0f);
        if (v > 0.0f) {
            int pos = count + __popcll(m & ((1ull << lane) - 1ull));
            if (pos < MAXDEG) nbr[(size_t)row * MAXDEG + pos] = base + lane;
        }
        count += __popcll(m);
    }
    if (lane == 0) deg[row] = count < MAXDEG ? count : MAXDEG;
}

// ---------------- x -> bf16 hi/lo ----------------
__global__ __launch_bounds__(256) void conv_x_k(const float* __restrict__ x,
                                                unsigned short* __restrict__ xh,
                                                unsigned short* __restrict__ xl, int n) {
    int i = blockIdx.x * 256 + threadIdx.x;
    if (i < n) {
        float v = x[i];
        unsigned short hb = f2bf(v);
        xh[i] = hb;
        xl[i] = f2bf(v - bf2f(hb));
    }
}

// ---------------- W[h][k][o] -> Wt[h][o][k] split to bf16 hi/lo ----------------
__global__ __launch_bounds__(256) void conv_wt_k(const float* __restrict__ W1,
                                                 const float* __restrict__ W2,
                                                 const float* __restrict__ W3,
                                                 const float* __restrict__ W4,
                                                 unsigned short* __restrict__ Wth,
                                                 unsigned short* __restrict__ Wtl) {
    __shared__ float t[64][65];
    int b = blockIdx.x;
    const float* W; int K; int local; size_t obase;
    if (b < 16)       { W = W1; K = 128; local = b;       obase = 0; }
    else if (b < 80)  { W = W2; K = 512; local = b - 16;  obase = 65536; }
    else if (b < 144) { W = W3; K = 512; local = b - 80;  obase = 327680; }
    else              { W = W4; K = 512; local = b - 144; obase = 589824; }
    int nkt = K >> 6;
    int h = local / nkt, kt = local - h * nkt;
    int k0 = kt * 64;
    int tid = threadIdx.x;
    for (int idx = tid; idx < 4096; idx += 256) {
        int r = idx >> 6, c = idx & 63;
        t[r][c] = W[(size_t)h * K * FO + (size_t)(k0 + r) * FO + c];
    }
    __syncthreads();
    for (int idx = tid; idx < 4096; idx += 256) {
        int o = idx >> 6, kk = idx & 63;
        float v = t[kk][o];
        unsigned short hb = f2bf(v);
        size_t dst = obase + (size_t)(h * FO + o) * K + k0 + kk;
        Wth[dst] = hb;
        Wtl[dst] = f2bf(v - bf2f(hb));
    }
}

// ---------------- split-bf16 MFMA GEMM, A via LDS, B direct from global (L2-resident) --------
// grid (NH, NN/64); block 256 = 4 waves (2x2 of 32x32); fused parallel e_src/e_dst epilogue
__global__ __launch_bounds__(256) void gemm_ee_k(const unsigned short* __restrict__ Ah,
                                                 const unsigned short* __restrict__ Al,
                                                 const unsigned short* __restrict__ Bh,
                                                 const unsigned short* __restrict__ Bl,
                                                 const float* __restrict__ a,
                                                 float* __restrict__ C,
                                                 float* __restrict__ esrc,
                                                 float* __restrict__ edst, int K) {
    __shared__ __align__(16) unsigned char smem[20480];
    typedef unsigned short AsT[64][80];
    typedef float CsT[68];
    AsT* As = reinterpret_cast<AsT*>(smem);            // As[2][64][80] hi/lo (20480 B)
    CsT* Cs = reinterpret_cast<CsT*>(smem);            // Cs[64][68] overlays As after main loop

    const int tid = threadIdx.x;
    const int h = blockIdx.x;
    const int r0 = blockIdx.y * 64;
    const int lane = tid & 63;
    const int wid = tid >> 6;
    const int wr = wid >> 1, wc = wid & 1;
    const int lr = lane & 15, lg = lane >> 4;

    const unsigned short* Bhh = Bh + (size_t)h * FO * K;
    const unsigned short* Bll = Bl + (size_t)h * FO * K;

    f32x4 acc[2][2];
    #pragma unroll
    for (int i = 0; i < 2; ++i)
        #pragma unroll
        for (int j = 0; j < 2; ++j) acc[i][j] = (f32x4){0.f, 0.f, 0.f, 0.f};

    for (int k0 = 0; k0 < K; k0 += 64) {
        // stage A tile (hi+lo) in LDS, chunk-XOR swizzled
        #pragma unroll
        for (int half = 0; half < 2; ++half) {
            int q = tid + half * 256;
            int row = q >> 3, cq = q & 7;
            int sw = (cq ^ (row & 7)) * 8;
            size_t ga = (size_t)(r0 + row) * K + k0 + cq * 8;
            *(bf16x8*)&As[0][row][sw] = *(const bf16x8*)(Ah + ga);
            *(bf16x8*)&As[1][row][sw] = *(const bf16x8*)(Al + ga);
        }
        __syncthreads();
        #pragma unroll
        for (int ks = 0; ks < 2; ++ks) {
            bf16x8 ah[2], al[2], bh[2], bl[2];
            int cq = ks * 4 + lg;
            #pragma unroll
            for (int i = 0; i < 2; ++i) {
                int row = wr * 32 + i * 16 + lr;
                int offa = (cq ^ (row & 7)) * 8;
                ah[i] = *(const bf16x8*)&As[0][row][offa];
                al[i] = *(const bf16x8*)&As[1][row][offa];
                int col = wc * 32 + i * 16 + lr;
                size_t gb = (size_t)col * K + k0 + cq * 8;
                bh[i] = *(const bf16x8*)(Bhh + gb);
                bl[i] = *(const bf16x8*)(Bll + gb);
            }
            #pragma unroll
            for (int i = 0; i < 2; ++i)
                #pragma unroll
                for (int j = 0; j < 2; ++j) {
                    acc[i][j] = __builtin_amdgcn_mfma_f32_16x16x32_bf16(ah[i], bh[j], acc[i][j], 0, 0, 0);
                    acc[i][j] = __builtin_amdgcn_mfma_f32_16x16x32_bf16(ah[i], bl[j], acc[i][j], 0, 0, 0);
                    acc[i][j] = __builtin_amdgcn_mfma_f32_16x16x32_bf16(al[i], bh[j], acc[i][j], 0, 0, 0);
                }
        }
        __syncthreads();
    }

    // stage C tile in LDS (fp32), overlaying As (loop-end barrier protects)
    #pragma unroll
    for (int i = 0; i < 2; ++i)
        #pragma unroll
        for (int j = 0; j < 2; ++j)
            #pragma unroll
            for (int r = 0; r < 4; ++r)
                Cs[wr * 32 + i * 16 + lg * 4 + r][wc * 32 + j * 16 + lr] = acc[i][j][r];
    __syncthreads();

    // coalesced float4 C stores
    #pragma unroll
    for (int it = 0; it < 4; ++it) {
        int idx = tid + it * 256;
        int r = idx >> 4, c4 = idx & 15;
        *(float4*)&C[(size_t)(r0 + r) * FCAT + h * FO + c4 * 4] = *(float4*)&Cs[r][c4 * 4];
    }

    // parallel fused e_src/e_dst: 4 lanes per row, 16 elems each, 2-step shuffle reduce
    {
        int r = tid >> 2, sub = tid & 3;
        const float* av = a + h * 2 * FO;
        float s = 0.0f, dd = 0.0f;
        #pragma unroll
        for (int k = 0; k < 16; ++k) {
            float v = Cs[r][sub * 16 + k];
            s = fmaf(v, av[sub * 16 + k], s);
            dd = fmaf(v, av[FO + sub * 16 + k], dd);
        }
        s += __shfl_xor(s, 1); s += __shfl_xor(s, 2);
        dd += __shfl_xor(dd, 1); dd += __shfl_xor(dd, 2);
        if (sub == 0) {
            esrc[h * NN + r0 + r] = s;
            edst[h * NN + r0 + r] = dd;
        }
    }
}

// ---------------- attention + aggregation (R1 structure): one wave per (n,h) ----------------
__global__ __launch_bounds__(256) void attn_agg_k(const float* __restrict__ Wh,
                                                  const float* __restrict__ esrc,
                                                  const float* __restrict__ edst,
                                                  const int* __restrict__ deg,
                                                  const int* __restrict__ nbr,
                                                  float* __restrict__ outp,
                                                  unsigned short* __restrict__ oh,
                                                  unsigned short* __restrict__ ol,
                                                  int write_f32) {
    __shared__ float pbuf[4][MAXDEG];
    __shared__ int jbuf[4][MAXDEG];
    const int ws = threadIdx.x >> 6;
    const int lane = threadIdx.x & 63;
    const int wid = blockIdx.x * 4 + ws;
    const int n = wid >> 3, h = wid & 7;
    const int d = deg[n];
    const int* nb = nbr + (size_t)n * MAXDEG;
    const float es = esrc[h * NN + n];

    for (int t = lane; t < d; t += 64) {
        int j = nb[t];
        float e = es + edst[h * NN + j];
        e = (e > 0.0f) ? e : ALPHA * e;
        jbuf[ws][t] = j;
        pbuf[ws][t] = e;
    }
    __syncthreads();
    float lm = -3.0e38f;
    for (int t = lane; t < d; t += 64) lm = fmaxf(lm, pbuf[ws][t]);
    #pragma unroll
    for (int off = 32; off; off >>= 1) lm = fmaxf(lm, __shfl_xor(lm, off));
    float lsum = 0.0f;
    for (int t = lane; t < d; t += 64) {
        float pv = __expf(pbuf[ws][t] - lm);
        pbuf[ws][t] = pv;
        lsum += pv;
    }
    #pragma unroll
    for (int off = 32; off; off >>= 1) lsum += __shfl_xor(lsum, off);
    __syncthreads();

    float acc = 0.0f;
    for (int t = 0; t < d; ++t) {
        int j = jbuf[ws][t];
        float pv = pbuf[ws][t];
        acc = fmaf(pv, Wh[(size_t)j * FCAT + h * FO + lane], acc);
    }
    acc /= lsum;
    float r = (acc > 0.0f) ? acc : (__expf(acc) - 1.0f);  // ELU
    size_t idx = (size_t)n * FCAT + h * FO + lane;
    if (write_f32) {
        outp[idx] = r;
    } else {
        unsigned short hb = f2bf(r);
        oh[idx] = hb;
        ol[idx] = f2bf(r - bf2f(hb));
    }
}

extern "C" void kernel_launch(void* const* d_in, const int* in_sizes, int n_in,
                              void* d_out, int out_size, void* d_ws, size_t ws_size,
                              hipStream_t stream) {
    const float* x   = (const float*)d_in[0];
    const float* adj = (const float*)d_in[1];
    const float* ap[4] = {(const float*)d_in[3], (const float*)d_in[5],
                          (const float*)d_in[7], (const float*)d_in[9]};
    float* out = (float*)d_out;

    char* p = (char*)d_ws;
    int* deg = (int*)p;              p += (size_t)NN * sizeof(int);
    int* nbr = (int*)p;              p += (size_t)NN * MAXDEG * sizeof(int);
    unsigned short* Ah = (unsigned short*)p; p += (size_t)NN * FCAT * 2;
    unsigned short* Al = (unsigned short*)p; p += (size_t)NN * FCAT * 2;
    float* WhF = (float*)p;          p += (size_t)NN * FCAT * sizeof(float);
    unsigned short* Wth = (unsigned short*)p; p += (size_t)851968 * 2;
    unsigned short* Wtl = (unsigned short*)p; p += (size_t)851968 * 2;
    float* esrc = (float*)p;         p += (size_t)NN * NH * sizeof(float);
    float* edst = (float*)p;         p += (size_t)NN * NH * sizeof(float);

    build_csr_k<<<NN, 64, 0, stream>>>(adj, deg, nbr);
    conv_x_k<<<(NN * 128 + 255) / 256, 256, 0, stream>>>(x, Ah, Al, NN * 128);
    conv_wt_k<<<208, 256, 0, stream>>>((const float*)d_in[2], (const float*)d_in[4],
                                       (const float*)d_in[6], (const float*)d_in[8],
                                       Wth, Wtl);

    const size_t woff[4] = {0, 65536, 327680, 589824};
    int K = 128;
    for (int L = 0; L < 4; ++L) {
        dim3 g(NH, NN / 64);
        gemm_ee_k<<<g, 256, 0, stream>>>(Ah, Al, Wth + woff[L], Wtl + woff[L],
                                         ap[L], WhF, esrc, edst, K);
        attn_agg_k<<<NN * NH / 4, 256, 0, stream>>>(WhF, esrc, edst, deg, nbr,
                                                    out, Ah, Al, L == 3 ? 1 : 0);
        K = FCAT;
    }
}

// Round 5
// 155.796 us; speedup vs baseline: 1.2193x; 1.1854x over previous
//
#include <hip/hip_runtime.h>
#include <math.h>

#define NN 3072
#define NH 8
#define FO 64
#define FCAT 512
#define MAXDEG 128
#define ALPHA 0.2f

typedef __attribute__((ext_vector_type(8))) short bf16x8;
typedef __attribute__((ext_vector_type(4))) float f32x4;

static __device__ __forceinline__ unsigned short f2bf(float v) {
    union { float f; unsigned u; } x; x.f = v;
    unsigned r = x.u + 0x7fffu + ((x.u >> 16) & 1u);
    return (unsigned short)(r >> 16);
}
static __device__ __forceinline__ float bf2f(unsigned short b) {
    union { unsigned u; float f; } x; x.u = ((unsigned)b) << 16;
    return x.f;
}

// ---------------- CSR build: one wave per row, ballot-ordered (deterministic) ----------------
__global__ __launch_bounds__(64) void build_csr_k(const float* __restrict__ adj,
                                                  int* __restrict__ deg,
                                                  int* __restrict__ nbr) {
    int row = blockIdx.x;
    int lane = threadIdx.x;
    const float* arow = adj + (size_t)row * NN;
    int count = 0;
    for (int base = 0; base < NN; base += 64) {
        float v = arow[base + lane];
        unsigned long long m = __ballot(v > 0.0f);
        if (v > 0.0f) {
            int pos = count + __popcll(m & ((1ull << lane) - 1ull));
            if (pos < MAXDEG) nbr[(size_t)row * MAXDEG + pos] = base + lane;
        }
        count += __popcll(m);
    }
    if (lane == 0) deg[row] = count < MAXDEG ? count : MAXDEG;
}

// ---------------- x -> bf16 hi/lo ----------------
__global__ __launch_bounds__(256) void conv_x_k(const float* __restrict__ x,
                                                unsigned short* __restrict__ xh,
                                                unsigned short* __restrict__ xl, int n) {
    int i = blockIdx.x * 256 + threadIdx.x;
    if (i < n) {
        float v = x[i];
        unsigned short hb = f2bf(v);
        xh[i] = hb;
        xl[i] = f2bf(v - bf2f(hb));
    }
}

// ---------------- W[h][k][o] -> Wt[h][o][k] split to bf16 hi/lo ----------------
__global__ __launch_bounds__(256) void conv_wt_k(const float* __restrict__ W1,
                                                 const float* __restrict__ W2,
                                                 const float* __restrict__ W3,
                                                 const float* __restrict__ W4,
                                                 unsigned short* __restrict__ Wth,
                                                 unsigned short* __restrict__ Wtl) {
    __shared__ float t[64][65];
    int b = blockIdx.x;
    const float* W; int K; int local; size_t obase;
    if (b < 16)       { W = W1; K = 128; local = b;       obase = 0; }
    else if (b < 80)  { W = W2; K = 512; local = b - 16;  obase = 65536; }
    else if (b < 144) { W = W3; K = 512; local = b - 80;  obase = 327680; }
    else              { W = W4; K = 512; local = b - 144; obase = 589824; }
    int nkt = K >> 6;
    int h = local / nkt, kt = local - h * nkt;
    int k0 = kt * 64;
    int tid = threadIdx.x;
    for (int idx = tid; idx < 4096; idx += 256) {
        int r = idx >> 6, c = idx & 63;
        t[r][c] = W[(size_t)h * K * FO + (size_t)(k0 + r) * FO + c];
    }
    __syncthreads();
    for (int idx = tid; idx < 4096; idx += 256) {
        int o = idx >> 6, kk = idx & 63;
        float v = t[kk][o];
        unsigned short hb = f2bf(v);
        size_t dst = obase + (size_t)(h * FO + o) * K + k0 + kk;
        Wth[dst] = hb;
        Wtl[dst] = f2bf(v - bf2f(hb));
    }
}

// ---------------- split-bf16 MFMA GEMM (A and B in LDS) + fused parallel ee epilogue --------
// grid (NH, NN/64); block 256 = 4 waves (2x2 of 32x32)
__global__ __launch_bounds__(256) void gemm_ee_k(const unsigned short* __restrict__ Ah,
                                                 const unsigned short* __restrict__ Al,
                                                 const unsigned short* __restrict__ Bh,
                                                 const unsigned short* __restrict__ Bl,
                                                 const float* __restrict__ a,
                                                 float* __restrict__ C,
                                                 float* __restrict__ esrc,
                                                 float* __restrict__ edst, int K) {
    __shared__ __align__(16) unsigned char smem[40960];
    typedef unsigned short AsT[64][80];
    typedef float CsT[68];
    AsT* As = reinterpret_cast<AsT*>(smem);            // As[2][64][80] hi/lo (20480 B)
    AsT* Bs = reinterpret_cast<AsT*>(smem + 20480);    // Bs[2][64][80]
    CsT* Cs = reinterpret_cast<CsT*>(smem);            // Cs[64][68] overlays As after main loop

    const int tid = threadIdx.x;
    const int h = blockIdx.x;
    const int r0 = blockIdx.y * 64;
    const int lane = tid & 63;
    const int wid = tid >> 6;
    const int wr = wid >> 1, wc = wid & 1;
    const int lr = lane & 15, lg = lane >> 4;

    const unsigned short* Bhh = Bh + (size_t)h * FO * K;
    const unsigned short* Bll = Bl + (size_t)h * FO * K;

    f32x4 acc[2][2];
    #pragma unroll
    for (int i = 0; i < 2; ++i)
        #pragma unroll
        for (int j = 0; j < 2; ++j) acc[i][j] = (f32x4){0.f, 0.f, 0.f, 0.f};

    for (int k0 = 0; k0 < K; k0 += 64) {
        #pragma unroll
        for (int half = 0; half < 2; ++half) {
            int q = tid + half * 256;
            int row = q >> 3, cq = q & 7;
            int sw = (cq ^ (row & 7)) * 8;
            size_t ga = (size_t)(r0 + row) * K + k0 + cq * 8;
            *(bf16x8*)&As[0][row][sw] = *(const bf16x8*)(Ah + ga);
            *(bf16x8*)&As[1][row][sw] = *(const bf16x8*)(Al + ga);
            size_t gb = (size_t)row * K + k0 + cq * 8;
            *(bf16x8*)&Bs[0][row][sw] = *(const bf16x8*)(Bhh + gb);
            *(bf16x8*)&Bs[1][row][sw] = *(const bf16x8*)(Bll + gb);
        }
        __syncthreads();
        #pragma unroll
        for (int ks = 0; ks < 2; ++ks) {
            bf16x8 ah[2], al[2], bh[2], bl[2];
            int cq = ks * 4 + lg;
            #pragma unroll
            for (int i = 0; i < 2; ++i) {
                int row = wr * 32 + i * 16 + lr;
                int offa = (cq ^ (row & 7)) * 8;
                ah[i] = *(const bf16x8*)&As[0][row][offa];
                al[i] = *(const bf16x8*)&As[1][row][offa];
                int col = wc * 32 + i * 16 + lr;
                int offb = (cq ^ (col & 7)) * 8;
                bh[i] = *(const bf16x8*)&Bs[0][col][offb];
                bl[i] = *(const bf16x8*)&Bs[1][col][offb];
            }
            #pragma unroll
            for (int i = 0; i < 2; ++i)
                #pragma unroll
                for (int j = 0; j < 2; ++j) {
                    acc[i][j] = __builtin_amdgcn_mfma_f32_16x16x32_bf16(ah[i], bh[j], acc[i][j], 0, 0, 0);
                    acc[i][j] = __builtin_amdgcn_mfma_f32_16x16x32_bf16(ah[i], bl[j], acc[i][j], 0, 0, 0);
                    acc[i][j] = __builtin_amdgcn_mfma_f32_16x16x32_bf16(al[i], bh[j], acc[i][j], 0, 0, 0);
                }
        }
        __syncthreads();
    }

    // stage C tile in LDS (fp32), overlaying As (loop-end barrier protects)
    #pragma unroll
    for (int i = 0; i < 2; ++i)
        #pragma unroll
        for (int j = 0; j < 2; ++j)
            #pragma unroll
            for (int r = 0; r < 4; ++r)
                Cs[wr * 32 + i * 16 + lg * 4 + r][wc * 32 + j * 16 + lr] = acc[i][j][r];
    __syncthreads();

    // coalesced float4 C stores
    #pragma unroll
    for (int it = 0; it < 4; ++it) {
        int idx = tid + it * 256;
        int r = idx >> 4, c4 = idx & 15;
        *(float4*)&C[(size_t)(r0 + r) * FCAT + h * FO + c4 * 4] = *(float4*)&Cs[r][c4 * 4];
    }

    // parallel fused e_src/e_dst: 4 lanes per row, 16 elems each, 2-step shuffle reduce
    {
        int r = tid >> 2, sub = tid & 3;
        const float* av = a + h * 2 * FO;
        float s = 0.0f, dd = 0.0f;
        #pragma unroll
        for (int k = 0; k < 16; ++k) {
            float v = Cs[r][sub * 16 + k];
            s = fmaf(v, av[sub * 16 + k], s);
            dd = fmaf(v, av[FO + sub * 16 + k], dd);
        }
        s += __shfl_xor(s, 1); s += __shfl_xor(s, 2);
        dd += __shfl_xor(dd, 1); dd += __shfl_xor(dd, 2);
        if (sub == 0) {
            esrc[h * NN + r0 + r] = s;
            edst[h * NN + r0 + r] = dd;
        }
    }
}

// ---------------- attention + aggregation (R1 structure): one wave per (n,h) ----------------
__global__ __launch_bounds__(256) void attn_agg_k(const float* __restrict__ Wh,
                                                  const float* __restrict__ esrc,
                                                  const float* __restrict__ edst,
                                                  const int* __restrict__ deg,
                                                  const int* __restrict__ nbr,
                                                  float* __restrict__ outp,
                                                  unsigned short* __restrict__ oh,
                                                  unsigned short* __restrict__ ol,
                                                  int write_f32) {
    __shared__ float pbuf[4][MAXDEG];
    __shared__ int jbuf[4][MAXDEG];
    const int ws = threadIdx.x >> 6;
    const int lane = threadIdx.x & 63;
    const int wid = blockIdx.x * 4 + ws;
    const int n = wid >> 3, h = wid & 7;
    const int d = deg[n];
    const int* nb = nbr + (size_t)n * MAXDEG;
    const float es = esrc[h * NN + n];

    for (int t = lane; t < d; t += 64) {
        int j = nb[t];
        float e = es + edst[h * NN + j];
        e = (e > 0.0f) ? e : ALPHA * e;
        jbuf[ws][t] = j;
        pbuf[ws][t] = e;
    }
    __syncthreads();
    float lm = -3.0e38f;
    for (int t = lane; t < d; t += 64) lm = fmaxf(lm, pbuf[ws][t]);
    #pragma unroll
    for (int off = 32; off; off >>= 1) lm = fmaxf(lm, __shfl_xor(lm, off));
    float lsum = 0.0f;
    for (int t = lane; t < d; t += 64) {
        float pv = __expf(pbuf[ws][t] - lm);
        pbuf[ws][t] = pv;
        lsum += pv;
    }
    #pragma unroll
    for (int off = 32; off; off >>= 1) lsum += __shfl_xor(lsum, off);
    __syncthreads();

    float acc = 0.0f;
    for (int t = 0; t < d; ++t) {
        int j = jbuf[ws][t];
        float pv = pbuf[ws][t];
        acc = fmaf(pv, Wh[(size_t)j * FCAT + h * FO + lane], acc);
    }
    acc /= lsum;
    float r = (acc > 0.0f) ? acc : (__expf(acc) - 1.0f);  // ELU
    size_t idx = (size_t)n * FCAT + h * FO + lane;
    if (write_f32) {
        outp[idx] = r;
    } else {
        unsigned short hb = f2bf(r);
        oh[idx] = hb;
        ol[idx] = f2bf(r - bf2f(hb));
    }
}

extern "C" void kernel_launch(void* const* d_in, const int* in_sizes, int n_in,
                              void* d_out, int out_size, void* d_ws, size_t ws_size,
                              hipStream_t stream) {
    const float* x   = (const float*)d_in[0];
    const float* adj = (const float*)d_in[1];
    const float* ap[4] = {(const float*)d_in[3], (const float*)d_in[5],
                          (const float*)d_in[7], (const float*)d_in[9]};
    float* out = (float*)d_out;

    char* p = (char*)d_ws;
    int* deg = (int*)p;              p += (size_t)NN * sizeof(int);
    int* nbr = (int*)p;              p += (size_t)NN * MAXDEG * sizeof(int);
    unsigned short* Ah = (unsigned short*)p; p += (size_t)NN * FCAT * 2;
    unsigned short* Al = (unsigned short*)p; p += (size_t)NN * FCAT * 2;
    float* WhF = (float*)p;          p += (size_t)NN * FCAT * sizeof(float);
    unsigned short* Wth = (unsigned short*)p; p += (size_t)851968 * 2;
    unsigned short* Wtl = (unsigned short*)p; p += (size_t)851968 * 2;
    float* esrc = (float*)p;         p += (size_t)NN * NH * sizeof(float);
    float* edst = (float*)p;         p += (size_t)NN * NH * sizeof(float);

    build_csr_k<<<NN, 64, 0, stream>>>(adj, deg, nbr);
    conv_x_k<<<(NN * 128 + 255) / 256, 256, 0, stream>>>(x, Ah, Al, NN * 128);
    conv_wt_k<<<208, 256, 0, stream>>>((const float*)d_in[2], (const float*)d_in[4],
                                       (const float*)d_in[6], (const float*)d_in[8],
                                       Wth, Wtl);

    const size_t woff[4] = {0, 65536, 327680, 589824};
    int K = 128;
    for (int L = 0; L < 4; ++L) {
        dim3 g(NH, NN / 64);
        gemm_ee_k<<<g, 256, 0, stream>>>(Ah, Al, Wth + woff[L], Wtl + woff[L],
                                         ap[L], WhF, esrc, edst, K);
        attn_agg_k<<<NN * NH / 4, 256, 0, stream>>>(WhF, esrc, edst, deg, nbr,
                                                    out, Ah, Al, L == 3 ? 1 : 0);
        K = FCAT;
    }
}

// Round 6
// 154.822 us; speedup vs baseline: 1.2270x; 1.0063x over previous
//
#include <hip/hip_runtime.h>
#include <math.h>

#define NN 3072
#define NH 8
#define FO 64
#define FCAT 512
#define MAXDEG 128
#define ALPHA 0.2f

typedef __attribute__((ext_vector_type(8))) short bf16x8;
typedef __attribute__((ext_vector_type(4))) float f32x4;

static __device__ __forceinline__ unsigned short f2bf(float v) {
    union { float f; unsigned u; } x; x.f = v;
    unsigned r = x.u + 0x7fffu + ((x.u >> 16) & 1u);
    return (unsigned short)(r >> 16);
}
static __device__ __forceinline__ float bf2f(unsigned short b) {
    union { unsigned u; float f; } x; x.u = ((unsigned)b) << 16;
    return x.f;
}

// ---------------- CSR build: one wave per row, ballot-ordered (deterministic) ----------------
__global__ __launch_bounds__(64) void build_csr_k(const float* __restrict__ adj,
                                                  int* __restrict__ deg,
                                                  int* __restrict__ nbr) {
    int row = blockIdx.x;
    int lane = threadIdx.x;
    const float* arow = adj + (size_t)row * NN;
    int count = 0;
    for (int base = 0; base < NN; base += 64) {
        float v = arow[base + lane];
        unsigned long long m = __ballot(v > 0.0f);
        if (v > 0.0f) {
            int pos = count + __popcll(m & ((1ull << lane) - 1ull));
            if (pos < MAXDEG) nbr[(size_t)row * MAXDEG + pos] = base + lane;
        }
        count += __popcll(m);
    }
    if (lane == 0) deg[row] = count < MAXDEG ? count : MAXDEG;
}

// ---------------- x -> bf16 hi/lo ----------------
__global__ __launch_bounds__(256) void conv_x_k(const float* __restrict__ x,
                                                unsigned short* __restrict__ xh,
                                                unsigned short* __restrict__ xl, int n) {
    int i = blockIdx.x * 256 + threadIdx.x;
    if (i < n) {
        float v = x[i];
        unsigned short hb = f2bf(v);
        xh[i] = hb;
        xl[i] = f2bf(v - bf2f(hb));
    }
}

// ---------------- W[h][k][o] -> Wt[h][o][k] split to bf16 hi/lo ----------------
__global__ __launch_bounds__(256) void conv_wt_k(const float* __restrict__ W1,
                                                 const float* __restrict__ W2,
                                                 const float* __restrict__ W3,
                                                 const float* __restrict__ W4,
                                                 unsigned short* __restrict__ Wth,
                                                 unsigned short* __restrict__ Wtl) {
    __shared__ float t[64][65];
    int b = blockIdx.x;
    const float* W; int K; int local; size_t obase;
    if (b < 16)       { W = W1; K = 128; local = b;       obase = 0; }
    else if (b < 80)  { W = W2; K = 512; local = b - 16;  obase = 65536; }
    else if (b < 144) { W = W3; K = 512; local = b - 80;  obase = 327680; }
    else              { W = W4; K = 512; local = b - 144; obase = 589824; }
    int nkt = K >> 6;
    int h = local / nkt, kt = local - h * nkt;
    int k0 = kt * 64;
    int tid = threadIdx.x;
    for (int idx = tid; idx < 4096; idx += 256) {
        int r = idx >> 6, c = idx & 63;
        t[r][c] = W[(size_t)h * K * FO + (size_t)(k0 + r) * FO + c];
    }
    __syncthreads();
    for (int idx = tid; idx < 4096; idx += 256) {
        int o = idx >> 6, kk = idx & 63;
        float v = t[kk][o];
        unsigned short hb = f2bf(v);
        size_t dst = obase + (size_t)(h * FO + o) * K + k0 + kk;
        Wth[dst] = hb;
        Wtl[dst] = f2bf(v - bf2f(hb));
    }
}

// ---------------- split-bf16 MFMA GEMM (A and B in LDS) + fused parallel ee epilogue --------
// grid (NH, NN/64); block 256 = 4 waves (2x2 of 32x32)
__global__ __launch_bounds__(256) void gemm_ee_k(const unsigned short* __restrict__ Ah,
                                                 const unsigned short* __restrict__ Al,
                                                 const unsigned short* __restrict__ Bh,
                                                 const unsigned short* __restrict__ Bl,
                                                 const float* __restrict__ a,
                                                 float* __restrict__ C,
                                                 float* __restrict__ esrc,
                                                 float* __restrict__ edst, int K) {
    __shared__ __align__(16) unsigned char smem[40960];
    typedef unsigned short AsT[64][80];
    typedef float CsT[68];
    AsT* As = reinterpret_cast<AsT*>(smem);            // As[2][64][80] hi/lo (20480 B)
    AsT* Bs = reinterpret_cast<AsT*>(smem + 20480);    // Bs[2][64][80]
    CsT* Cs = reinterpret_cast<CsT*>(smem);            // Cs[64][68] overlays As after main loop

    const int tid = threadIdx.x;
    const int h = blockIdx.x;
    const int r0 = blockIdx.y * 64;
    const int lane = tid & 63;
    const int wid = tid >> 6;
    const int wr = wid >> 1, wc = wid & 1;
    const int lr = lane & 15, lg = lane >> 4;

    const unsigned short* Bhh = Bh + (size_t)h * FO * K;
    const unsigned short* Bll = Bl + (size_t)h * FO * K;

    f32x4 acc[2][2];
    #pragma unroll
    for (int i = 0; i < 2; ++i)
        #pragma unroll
        for (int j = 0; j < 2; ++j) acc[i][j] = (f32x4){0.f, 0.f, 0.f, 0.f};

    for (int k0 = 0; k0 < K; k0 += 64) {
        #pragma unroll
        for (int half = 0; half < 2; ++half) {
            int q = tid + half * 256;
            int row = q >> 3, cq = q & 7;
            int sw = (cq ^ (row & 7)) * 8;
            size_t ga = (size_t)(r0 + row) * K + k0 + cq * 8;
            *(bf16x8*)&As[0][row][sw] = *(const bf16x8*)(Ah + ga);
            *(bf16x8*)&As[1][row][sw] = *(const bf16x8*)(Al + ga);
            size_t gb = (size_t)row * K + k0 + cq * 8;
            *(bf16x8*)&Bs[0][row][sw] = *(const bf16x8*)(Bhh + gb);
            *(bf16x8*)&Bs[1][row][sw] = *(const bf16x8*)(Bll + gb);
        }
        __syncthreads();
        #pragma unroll
        for (int ks = 0; ks < 2; ++ks) {
            bf16x8 ah[2], al[2], bh[2], bl[2];
            int cq = ks * 4 + lg;
            #pragma unroll
            for (int i = 0; i < 2; ++i) {
                int row = wr * 32 + i * 16 + lr;
                int offa = (cq ^ (row & 7)) * 8;
                ah[i] = *(const bf16x8*)&As[0][row][offa];
                al[i] = *(const bf16x8*)&As[1][row][offa];
                int col = wc * 32 + i * 16 + lr;
                int offb = (cq ^ (col & 7)) * 8;
                bh[i] = *(const bf16x8*)&Bs[0][col][offb];
                bl[i] = *(const bf16x8*)&Bs[1][col][offb];
            }
            #pragma unroll
            for (int i = 0; i < 2; ++i)
                #pragma unroll
                for (int j = 0; j < 2; ++j) {
                    acc[i][j] = __builtin_amdgcn_mfma_f32_16x16x32_bf16(ah[i], bh[j], acc[i][j], 0, 0, 0);
                    acc[i][j] = __builtin_amdgcn_mfma_f32_16x16x32_bf16(ah[i], bl[j], acc[i][j], 0, 0, 0);
                    acc[i][j] = __builtin_amdgcn_mfma_f32_16x16x32_bf16(al[i], bh[j], acc[i][j], 0, 0, 0);
                }
        }
        __syncthreads();
    }

    // stage C tile in LDS (fp32), overlaying As (loop-end barrier protects)
    #pragma unroll
    for (int i = 0; i < 2; ++i)
        #pragma unroll
        for (int j = 0; j < 2; ++j)
            #pragma unroll
            for (int r = 0; r < 4; ++r)
                Cs[wr * 32 + i * 16 + lg * 4 + r][wc * 32 + j * 16 + lr] = acc[i][j][r];
    __syncthreads();

    // coalesced float4 C stores
    #pragma unroll
    for (int it = 0; it < 4; ++it) {
        int idx = tid + it * 256;
        int r = idx >> 4, c4 = idx & 15;
        *(float4*)&C[(size_t)(r0 + r) * FCAT + h * FO + c4 * 4] = *(float4*)&Cs[r][c4 * 4];
    }

    // parallel fused e_src/e_dst: 4 lanes per row, 16 elems each, 2-step shuffle reduce
    {
        int r = tid >> 2, sub = tid & 3;
        const float* av = a + h * 2 * FO;
        float s = 0.0f, dd = 0.0f;
        #pragma unroll
        for (int k = 0; k < 16; ++k) {
            float v = Cs[r][sub * 16 + k];
            s = fmaf(v, av[sub * 16 + k], s);
            dd = fmaf(v, av[FO + sub * 16 + k], dd);
        }
        s += __shfl_xor(s, 1); s += __shfl_xor(s, 2);
        dd += __shfl_xor(dd, 1); dd += __shfl_xor(dd, 2);
        if (sub == 0) {
            esrc[h * NN + r0 + r] = s;
            edst[h * NN + r0 + r] = dd;
        }
    }
}

// ---------------- attention + aggregation: h-major block order for L2 locality -------------
// grid = NH * NN/4 blocks; block b: h = b/768, waves cover n = (b%768)*4 + ws
__global__ __launch_bounds__(256) void attn_agg_k(const float* __restrict__ Wh,
                                                  const float* __restrict__ esrc,
                                                  const float* __restrict__ edst,
                                                  const int* __restrict__ deg,
                                                  const int* __restrict__ nbr,
                                                  float* __restrict__ outp,
                                                  unsigned short* __restrict__ oh,
                                                  unsigned short* __restrict__ ol,
                                                  int write_f32) {
    __shared__ float pbuf[4][MAXDEG];
    __shared__ int jbuf[4][MAXDEG];
    const int ws = threadIdx.x >> 6;
    const int lane = threadIdx.x & 63;
    const int h = blockIdx.x / (NN / 4);
    const int n = (blockIdx.x % (NN / 4)) * 4 + ws;
    const int d = deg[n];
    const int* nb = nbr + (size_t)n * MAXDEG;
    const float es = esrc[h * NN + n];
    const float* ed = edst + h * NN;

    // no __syncthreads needed: each wave touches only its own pbuf[ws]/jbuf[ws]
    for (int t = lane; t < d; t += 64) {
        int j = nb[t];
        float e = es + ed[j];
        e = (e > 0.0f) ? e : ALPHA * e;
        jbuf[ws][t] = j;
        pbuf[ws][t] = e;
    }
    float lm = -3.0e38f;
    for (int t = lane; t < d; t += 64) lm = fmaxf(lm, pbuf[ws][t]);
    #pragma unroll
    for (int off = 32; off; off >>= 1) lm = fmaxf(lm, __shfl_xor(lm, off));
    float lsum = 0.0f;
    for (int t = lane; t < d; t += 64) {
        float pv = __expf(pbuf[ws][t] - lm);
        pbuf[ws][t] = pv;
        lsum += pv;
    }
    #pragma unroll
    for (int off = 32; off; off >>= 1) lsum += __shfl_xor(lsum, off);

    // gather: 4-way unrolled, 4 independent accumulators (4 loads in flight)
    const float* whb = Wh + h * FO + lane;
    float a0 = 0.f, a1 = 0.f, a2 = 0.f, a3 = 0.f;
    int t = 0;
    for (; t + 3 < d; t += 4) {
        a0 = fmaf(pbuf[ws][t + 0], whb[(size_t)jbuf[ws][t + 0] * FCAT], a0);
        a1 = fmaf(pbuf[ws][t + 1], whb[(size_t)jbuf[ws][t + 1] * FCAT], a1);
        a2 = fmaf(pbuf[ws][t + 2], whb[(size_t)jbuf[ws][t + 2] * FCAT], a2);
        a3 = fmaf(pbuf[ws][t + 3], whb[(size_t)jbuf[ws][t + 3] * FCAT], a3);
    }
    for (; t < d; ++t)
        a0 = fmaf(pbuf[ws][t], whb[(size_t)jbuf[ws][t] * FCAT], a0);
    float acc = (a0 + a1) + (a2 + a3);
    acc /= lsum;
    float r = (acc > 0.0f) ? acc : (__expf(acc) - 1.0f);  // ELU
    size_t idx = (size_t)n * FCAT + h * FO + lane;
    if (write_f32) {
        outp[idx] = r;
    } else {
        unsigned short hb = f2bf(r);
        oh[idx] = hb;
        ol[idx] = f2bf(r - bf2f(hb));
    }
}

extern "C" void kernel_launch(void* const* d_in, const int* in_sizes, int n_in,
                              void* d_out, int out_size, void* d_ws, size_t ws_size,
                              hipStream_t stream) {
    const float* x   = (const float*)d_in[0];
    const float* adj = (const float*)d_in[1];
    const float* ap[4] = {(const float*)d_in[3], (const float*)d_in[5],
                          (const float*)d_in[7], (const float*)d_in[9]};
    float* out = (float*)d_out;

    char* p = (char*)d_ws;
    int* deg = (int*)p;              p += (size_t)NN * sizeof(int);
    int* nbr = (int*)p;              p += (size_t)NN * MAXDEG * sizeof(int);
    unsigned short* Ah = (unsigned short*)p; p += (size_t)NN * FCAT * 2;
    unsigned short* Al = (unsigned short*)p; p += (size_t)NN * FCAT * 2;
    float* WhF = (float*)p;          p += (size_t)NN * FCAT * sizeof(float);
    unsigned short* Wth = (unsigned short*)p; p += (size_t)851968 * 2;
    unsigned short* Wtl = (unsigned short*)p; p += (size_t)851968 * 2;
    float* esrc = (float*)p;         p += (size_t)NN * NH * sizeof(float);
    float* edst = (float*)p;         p += (size_t)NN * NH * sizeof(float);

    build_csr_k<<<NN, 64, 0, stream>>>(adj, deg, nbr);
    conv_x_k<<<(NN * 128 + 255) / 256, 256, 0, stream>>>(x, Ah, Al, NN * 128);
    conv_wt_k<<<208, 256, 0, stream>>>((const float*)d_in[2], (const float*)d_in[4],
                                       (const float*)d_in[6], (const float*)d_in[8],
                                       Wth, Wtl);

    const size_t woff[4] = {0, 65536, 327680, 589824};
    int K = 128;
    for (int L = 0; L < 4; ++L) {
        dim3 g(NH, NN / 64);
        gemm_ee_k<<<g, 256, 0, stream>>>(Ah, Al, Wth + woff[L], Wtl + woff[L],
                                         ap[L], WhF, esrc, edst, K);
        attn_agg_k<<<NH * (NN / 4), 256, 0, stream>>>(WhF, esrc, edst, deg, nbr,
                                                      out, Ah, Al, L == 3 ? 1 : 0);
        K = FCAT;
    }
}